// Round 1
// baseline (413.146 us; speedup 1.0000x reference)
//
#include <hip/hip_runtime.h>
#include <stdint.h>

typedef __attribute__((ext_vector_type(8))) short bf16x8;
typedef __attribute__((ext_vector_type(4))) float f32x4;

#define SEQ 4096
#define NB 4

__device__ __forceinline__ float bf2f(unsigned short u) {
  union { unsigned int i; float f; } v; v.i = ((unsigned int)u) << 16; return v.f;
}
__device__ __forceinline__ unsigned short f2bf(float f) {
  union { float f; unsigned int i; } v; v.f = f;
  unsigned int u = v.i;
  u = u + 0x7FFFu + ((u >> 16) & 1u);
  return (unsigned short)(u >> 16);
}
__device__ __forceinline__ float sigm(float x) { return 1.0f / (1.0f + __expf(-x)); }

// ---------------- conversion kernels ----------------

__global__ void cvt_x_kernel(const float* __restrict__ in, unsigned short* __restrict__ out, int n8) {
  int i = blockIdx.x * blockDim.x + threadIdx.x;
  int stride = gridDim.x * blockDim.x;
  for (; i < n8; i += stride) {
    const float4* p = (const float4*)in + (size_t)i * 2;
    float4 a = p[0], b = p[1];
    union { unsigned short u[8]; uint4 v; } r;
    r.u[0] = f2bf(a.x); r.u[1] = f2bf(a.y); r.u[2] = f2bf(a.z); r.u[3] = f2bf(a.w);
    r.u[4] = f2bf(b.x); r.u[5] = f2bf(b.y); r.u[6] = f2bf(b.z); r.u[7] = f2bf(b.w);
    ((uint4*)out)[i] = r.v;
  }
}

// transpose fp32 [K][N] -> bf16 [N][K]
__global__ void tconv32_kernel(const float* __restrict__ src, unsigned short* __restrict__ dst,
                               int K, int N) {
  __shared__ float t[32][33];
  int n0 = blockIdx.x * 32, k0 = blockIdx.y * 32;
  int tx = threadIdx.x & 31, ty = threadIdx.x >> 5;
#pragma unroll
  for (int i = 0; i < 32; i += 8)
    t[ty + i][tx] = src[(size_t)(k0 + ty + i) * N + n0 + tx];
  __syncthreads();
#pragma unroll
  for (int i = 0; i < 32; i += 8)
    dst[(size_t)(n0 + ty + i) * K + k0 + tx] = f2bf(t[tx][ty + i]);
}

__global__ void concat_bias_kernel(const float* b0, const float* b1, const float* b2,
                                   const float* b3, float* b4) {
  int i = blockIdx.x * 256 + threadIdx.x;  // 0..4095
  const float* p = (i < 1024) ? b0 : (i < 2048) ? b1 : (i < 3072) ? b2 : b3;
  b4[i] = p[i & 1023];
}

// ---------------- GEMM (A [M][K] bf16, BT [N][K] bf16) ----------------
// 128x128 tile, BK=64, 256 threads = 4 waves (2x2), 16x16x32 MFMA.
// MODE 0: epilogue bias + gate activation -> bf16 ACT (ldc=4096)
// MODE 1: epilogue bias -> fp32 out (ldc=1024)

template <int MODE>
__global__ __launch_bounds__(256) void gemm_bt_kernel(
    const unsigned short* __restrict__ A, const unsigned short* __restrict__ BT,
    const float* __restrict__ bias, void* __restrict__ Cout, int K) {
  __shared__ unsigned short As[128 * 64];
  __shared__ unsigned short Bs[128 * 64];

  const int tid = threadIdx.x;
  const int lane = tid & 63;
  const int wv = tid >> 6;
  const int wm = wv >> 1, wn = wv & 1;
  const int lo = lane & 15, hi = lane >> 4;
  const int m0 = blockIdx.y * 128;
  const int n0 = blockIdx.x * 128;

  f32x4 acc[4][4];
#pragma unroll
  for (int i = 0; i < 4; ++i)
#pragma unroll
    for (int j = 0; j < 4; ++j) acc[i][j] = (f32x4){0.f, 0.f, 0.f, 0.f};

  const int nIter = K >> 6;
  for (int kt = 0; kt < nIter; ++kt) {
    const int k0 = kt << 6;
    __syncthreads();
    // stage A and B tiles: 16KB each, 4 issues x 256 threads x 16B
    // LDS[o] holds element (row=o>>7, kbyte=(o&127)^((row&7)<<4))  (pre-swizzled source)
#pragma unroll
    for (int j = 0; j < 4; ++j) {
      int o = j * 4096 + tid * 16;
      int row = o >> 7;
      int kb = (o & 127) ^ ((row & 7) << 4);
      const unsigned short* srcA = A + (size_t)(m0 + row) * K + k0 + (kb >> 1);
      const unsigned short* srcB = BT + (size_t)(n0 + row) * K + k0 + (kb >> 1);
      unsigned short* dstA = &As[j * 2048 + wv * 512];
      unsigned short* dstB = &Bs[j * 2048 + wv * 512];
      __builtin_amdgcn_global_load_lds((const __attribute__((address_space(1))) void*)srcA,
                                       (__attribute__((address_space(3))) void*)dstA, 16, 0, 0);
      __builtin_amdgcn_global_load_lds((const __attribute__((address_space(1))) void*)srcB,
                                       (__attribute__((address_space(3))) void*)dstB, 16, 0, 0);
    }
    __syncthreads();

    bf16x8 af[4][2], bfr[4][2];
#pragma unroll
    for (int mi = 0; mi < 4; ++mi) {
      int row = wm * 64 + mi * 16 + lo;
#pragma unroll
      for (int ks = 0; ks < 2; ++ks) {
        int kb = (ks * 64 + hi * 16) ^ ((row & 7) << 4);
        af[mi][ks] = *(const bf16x8*)(As + row * 64 + (kb >> 1));
      }
    }
#pragma unroll
    for (int ni = 0; ni < 4; ++ni) {
      int row = wn * 64 + ni * 16 + lo;
#pragma unroll
      for (int ks = 0; ks < 2; ++ks) {
        int kb = (ks * 64 + hi * 16) ^ ((row & 7) << 4);
        bfr[ni][ks] = *(const bf16x8*)(Bs + row * 64 + (kb >> 1));
      }
    }
#pragma unroll
    for (int ks = 0; ks < 2; ++ks)
#pragma unroll
      for (int mi = 0; mi < 4; ++mi)
#pragma unroll
        for (int ni = 0; ni < 4; ++ni)
          acc[mi][ni] = __builtin_amdgcn_mfma_f32_16x16x32_bf16(af[mi][ks], bfr[ni][ks],
                                                                acc[mi][ni], 0, 0, 0);
  }

  // epilogue: C/D layout col=lane&15, row=(lane>>4)*4+reg
#pragma unroll
  for (int mi = 0; mi < 4; ++mi) {
#pragma unroll
    for (int ni = 0; ni < 4; ++ni) {
      int col = n0 + wn * 64 + ni * 16 + lo;
      int rb = m0 + wm * 64 + mi * 16 + hi * 4;
      float bcol = bias[col];
      f32x4 v = acc[mi][ni];
      if (MODE == 0) {
        unsigned short* ACTp = (unsigned short*)Cout;
        bool isz = ((col >> 10) & 1) == 0;  // groups 0,2 are z-gates
#pragma unroll
        for (int r = 0; r < 4; ++r) {
          float x = v[r] + bcol;
          float res;
          if (isz) res = sigm(-x);                       // a = 1 - z
          else res = (x >= 0.f) ? (x + 0.5f) : sigm(x);  // g(x)
          ACTp[(size_t)(rb + r) * 4096 + col] = f2bf(res);
        }
      } else {
        float* Op = (float*)Cout;
#pragma unroll
        for (int r = 0; r < 4; ++r) Op[(size_t)(rb + r) * 1024 + col] = v[r] + bcol;
      }
    }
  }
}

// ---------------- chunked linear scan ----------------
// ACT cols: [0,1024)=a_f  [1024,2048)=g_f  [2048,3072)=a_b  [3072,4096)=g_b
// recurrence: h = a*h + (1-a)*g ; chunk length 128, 32 chunks.

__global__ __launch_bounds__(256) void scan_phase1_kernel(const unsigned short* __restrict__ ACT,
                                                          float* __restrict__ CHA,
                                                          float* __restrict__ CHB) {
  int tid = threadIdx.x;
  int cb = blockIdx.x & 3;
  int chunk = (blockIdx.x >> 2) & 31;
  int b = (blockIdx.x >> 7) & 3;
  int dir = (blockIdx.x >> 9) & 1;
  int c = cb * 256 + tid;
  int t0 = chunk * 128;
  size_t colA = (size_t)dir * 2048 + c;
  float Ap = 1.f, Bv = 0.f;
  for (int i = 0; i < 128; ++i) {
    int t = t0 + i;
    int s = dir ? (SEQ - 1 - t) : t;
    size_t base = ((size_t)b * SEQ + s) * 4096;
    float a = bf2f(ACT[base + colA]);
    float g = bf2f(ACT[base + colA + 1024]);
    Bv = a * Bv + (1.f - a) * g;
    Ap *= a;
  }
  size_t o = ((size_t)(dir * 4 + b) * 32 + chunk) * 1024 + c;
  CHA[o] = Ap;
  CHB[o] = Bv;
}

__global__ __launch_bounds__(256) void scan_phase2_kernel(const float* __restrict__ CHA,
                                                          const float* __restrict__ CHB,
                                                          float* __restrict__ HINIT) {
  int idx = blockIdx.x * 256 + threadIdx.x;  // 8192 = dir*4096 + b*1024 + c
  int c = idx & 1023;
  int db = idx >> 10;  // dir*4 + b
  float h = 0.f;
  for (int ck = 0; ck < 32; ++ck) {
    size_t o = ((size_t)db * 32 + ck) * 1024 + c;
    HINIT[o] = h;
    h = CHA[o] * h + CHB[o];
  }
}

__global__ __launch_bounds__(256) void scan_phase3_kernel(const unsigned short* __restrict__ ACT,
                                                          const float* __restrict__ HINIT,
                                                          unsigned short* __restrict__ HCAT) {
  int tid = threadIdx.x;
  int cb = blockIdx.x & 3;
  int chunk = (blockIdx.x >> 2) & 31;
  int b = (blockIdx.x >> 7) & 3;
  int dir = (blockIdx.x >> 9) & 1;
  int c = cb * 256 + tid;
  int t0 = chunk * 128;
  size_t colA = (size_t)dir * 2048 + c;
  float h = HINIT[((size_t)(dir * 4 + b) * 32 + chunk) * 1024 + c];
  for (int i = 0; i < 128; ++i) {
    int t = t0 + i;
    int s = dir ? (SEQ - 1 - t) : t;
    size_t base = ((size_t)b * SEQ + s) * 4096;
    float a = bf2f(ACT[base + colA]);
    float g = bf2f(ACT[base + colA + 1024]);
    h = a * h + (1.f - a) * g;
    HCAT[((size_t)b * SEQ + t) * 2048 + dir * 1024 + c] = f2bf(h);
  }
}

// ---------------- launcher ----------------

extern "C" void kernel_launch(void* const* d_in, const int* in_sizes, int n_in,
                              void* d_out, int out_size, void* d_ws, size_t ws_size,
                              hipStream_t stream) {
  (void)in_sizes; (void)n_in; (void)out_size; (void)ws_size;
  const float* x     = (const float*)d_in[0];
  const float* Wz_f  = (const float*)d_in[1];
  const float* bz_f  = (const float*)d_in[2];
  const float* Wh_f  = (const float*)d_in[3];
  const float* bh_f  = (const float*)d_in[4];
  const float* Wz_b  = (const float*)d_in[5];
  const float* bz_b  = (const float*)d_in[6];
  const float* Wh_b  = (const float*)d_in[7];
  const float* bh_b  = (const float*)d_in[8];
  const float* W_out = (const float*)d_in[9];
  const float* b_out = (const float*)d_in[10];

  char* ws = (char*)d_ws;
  size_t off = 0;
  auto alloc = [&](size_t bytes) {
    char* p = ws + off;
    off = (off + bytes + 255) & ~(size_t)255;
    return p;
  };
  const size_t M = 16384;  // B*S
  unsigned short* xb    = (unsigned short*)alloc(M * 1024 * 2);        // x bf16 [M][1024]
  unsigned short* WT4   = (unsigned short*)alloc(4096ull * 1024 * 2);  // [4096][1024] K-major
  unsigned short* WTout = (unsigned short*)alloc(1024ull * 2048 * 2);  // [1024][2048] K-major
  unsigned short* ACT   = (unsigned short*)alloc(M * 4096 * 2);        // bf16 gates
  unsigned short* HCAT  = (unsigned short*)alloc(M * 2048 * 2);        // bf16 hidden concat
  float* CHA   = (float*)alloc(262144ull * 4);
  float* CHB   = (float*)alloc(262144ull * 4);
  float* HINIT = (float*)alloc(262144ull * 4);
  float* b4    = (float*)alloc(4096 * 4);

  // 1) convert x to bf16
  cvt_x_kernel<<<2048, 256, 0, stream>>>(x, xb, (int)(M * 1024 / 8));

  // 2) transpose+convert weights: WT4 groups {Wz_f, Wh_f, Wz_b, Wh_b}
  tconv32_kernel<<<dim3(32, 32), 256, 0, stream>>>(Wz_f, WT4 + 0 * 1048576, 1024, 1024);
  tconv32_kernel<<<dim3(32, 32), 256, 0, stream>>>(Wh_f, WT4 + 1 * 1048576, 1024, 1024);
  tconv32_kernel<<<dim3(32, 32), 256, 0, stream>>>(Wz_b, WT4 + 2 * 1048576, 1024, 1024);
  tconv32_kernel<<<dim3(32, 32), 256, 0, stream>>>(Wh_b, WT4 + 3 * 1048576, 1024, 1024);
  tconv32_kernel<<<dim3(32, 64), 256, 0, stream>>>(W_out, WTout, 2048, 1024);
  concat_bias_kernel<<<16, 256, 0, stream>>>(bz_f, bh_f, bz_b, bh_b, b4);

  // 3) fused input GEMM + activations -> ACT
  gemm_bt_kernel<0><<<dim3(32, 128), 256, 0, stream>>>(xb, WT4, b4, (void*)ACT, 1024);

  // 4) 3-phase linear scan -> HCAT
  scan_phase1_kernel<<<1024, 256, 0, stream>>>(ACT, CHA, CHB);
  scan_phase2_kernel<<<32, 256, 0, stream>>>(CHA, CHB, HINIT);
  scan_phase3_kernel<<<1024, 256, 0, stream>>>(ACT, HINIT, HCAT);

  // 5) output GEMM + bias -> d_out (fp32)
  gemm_bt_kernel<1><<<dim3(8, 128), 256, 0, stream>>>(HCAT, WTout, b_out, d_out, 2048);
}

// Round 4
// 337.828 us; speedup vs baseline: 1.2229x; 1.2229x over previous
//
#include <hip/hip_runtime.h>
#include <stdint.h>

typedef __attribute__((ext_vector_type(8))) short bf16x8;
typedef __attribute__((ext_vector_type(4))) float f32x4;

#define SEQ 4096

__device__ __forceinline__ float bf2f(unsigned short u) {
  union { unsigned int i; float f; } v; v.i = ((unsigned int)u) << 16; return v.f;
}
__device__ __forceinline__ unsigned short f2bf(float f) {
  union { float f; unsigned int i; } v; v.f = f;
  unsigned int u = v.i;
  u = u + 0x7FFFu + ((u >> 16) & 1u);
  return (unsigned short)(u >> 16);
}
__device__ __forceinline__ float sigm(float x) { return 1.0f / (1.0f + __expf(-x)); }

// ---------------- conversion kernels ----------------

__global__ void cvt_x_kernel(const float* __restrict__ in, unsigned short* __restrict__ out, int n8) {
  int i = blockIdx.x * blockDim.x + threadIdx.x;
  int stride = gridDim.x * blockDim.x;
  for (; i < n8; i += stride) {
    const float4* p = (const float4*)in + (size_t)i * 2;
    float4 a = p[0], b = p[1];
    union { unsigned short u[8]; uint4 v; } r;
    r.u[0] = f2bf(a.x); r.u[1] = f2bf(a.y); r.u[2] = f2bf(a.z); r.u[3] = f2bf(a.w);
    r.u[4] = f2bf(b.x); r.u[5] = f2bf(b.y); r.u[6] = f2bf(b.z); r.u[7] = f2bf(b.w);
    ((uint4*)out)[i] = r.v;
  }
}

// transpose fp32 [K][N] -> bf16 [N][K]
__global__ void tconv32_kernel(const float* __restrict__ src, unsigned short* __restrict__ dst,
                               int K, int N) {
  __shared__ float t[32][33];
  int n0 = blockIdx.x * 32, k0 = blockIdx.y * 32;
  int tx = threadIdx.x & 31, ty = threadIdx.x >> 5;
#pragma unroll
  for (int i = 0; i < 32; i += 8)
    t[ty + i][tx] = src[(size_t)(k0 + ty + i) * N + n0 + tx];
  __syncthreads();
#pragma unroll
  for (int i = 0; i < 32; i += 8)
    dst[(size_t)(n0 + ty + i) * K + k0 + tx] = f2bf(t[tx][ty + i]);
}

__global__ void concat_bias_kernel(const float* b0, const float* b1, const float* b2,
                                   const float* b3, float* b4) {
  int i = blockIdx.x * 256 + threadIdx.x;  // 0..4095
  const float* p = (i < 1024) ? b0 : (i < 2048) ? b1 : (i < 3072) ? b2 : b3;
  b4[i] = p[i & 1023];
}

// ---------------- 256x256 phase-split GEMM (A [M][K] bf16, BT [N][K] bf16) --------
// BK=32, 512 threads = 8 waves (2M x 4N), dbuf LDS 64KB, counted vmcnt prefetch.
// MODE 0: epilogue bias + gate activation -> bf16 ACT (ldc=4096)
// MODE 1: epilogue bias -> fp32 out (ldc=1024)

template <int MODE>
__global__ __launch_bounds__(512, 2) void gemm256_kernel(
    const unsigned short* __restrict__ A, const unsigned short* __restrict__ BT,
    const float* __restrict__ bias, void* __restrict__ Cout, int K, int NT) {
  // LDS layout (ushort idx): A buf b at b*8192, B buf b at 16384 + b*8192.
  // tile = 256 rows x 32 k; row = 64 bytes; swizzle: kbyte ^= ((row>>1)&3)<<4
  __shared__ unsigned short lds[32768];  // 64 KB

  const int tid = threadIdx.x;
  const int lane = tid & 63;
  const int wv = tid >> 6;
  const int wm = wv >> 2;   // 0..1 -> rows wm*128..+128
  const int wn = wv & 3;    // 0..3 -> cols wn*64..+64
  const int lo = lane & 15, hi = lane >> 4;

  // bijective XCD swizzle (gridDim.x % 8 == 0), then mt-major so consecutive
  // blocks in a chunk share the A panel.
  const int nwg = gridDim.x;
  const int bid = blockIdx.x;
  const int cpx = nwg >> 3;
  const int sw = (bid & 7) * cpx + (bid >> 3);
  const int mt = sw / NT, nt = sw - mt * NT;
  const int m0 = mt << 8, n0 = nt << 8;

  // staging source (per-thread, pre-swizzled)
  const int srow = tid >> 2;                                // 0..127 (+j*128)
  const int skb = (((tid & 3) ^ ((tid >> 3) & 3)) << 4);    // swizzled k-byte
  const unsigned short* pA0 = A + (size_t)(m0 + srow) * K + (skb >> 1);
  const unsigned short* pA1 = pA0 + (size_t)128 * K;
  const unsigned short* pB0 = BT + (size_t)(n0 + srow) * K + (skb >> 1);
  const unsigned short* pB1 = pB0 + (size_t)128 * K;
  const int dstBase = wv << 9;  // wave-uniform LDS dst (ushorts); HW adds lane*16B

#define GLL(SRC, DIDX)                                                                  \
  __builtin_amdgcn_global_load_lds((const __attribute__((address_space(1))) void*)(SRC), \
                                   (__attribute__((address_space(3))) void*)&lds[DIDX], \
                                   16, 0, 0)
#define STAGE(KT, BUF)                                   \
  do {                                                   \
    const int ko_ = (KT) << 5;                           \
    GLL(pA0 + ko_, (BUF) * 8192 + dstBase);              \
    GLL(pA1 + ko_, (BUF) * 8192 + 4096 + dstBase);       \
    GLL(pB0 + ko_, 16384 + (BUF) * 8192 + dstBase);      \
    GLL(pB1 + ko_, 16384 + (BUF) * 8192 + 4096 + dstBase); \
  } while (0)

  f32x4 acc[8][4];
#pragma unroll
  for (int i = 0; i < 8; ++i)
#pragma unroll
    for (int j = 0; j < 4; ++j) acc[i][j] = (f32x4){0.f, 0.f, 0.f, 0.f};

  // fragment read pieces (ushort indices); swizzle uniform per lane
  const int swz = ((lo >> 1) & 3) << 4;         // byte swizzle
  const int kof = ((hi << 4) ^ swz) >> 1;       // ushort offset within 64B row
  const int aRow = wm * 128 + lo;               // + mi*16
  const int bRow = wn * 64 + lo;                // + ni*16

  const int nT = K >> 5;
  STAGE(0, 0);
  for (int kt = 0; kt < nT; ++kt) {
    const int buf = kt & 1;
    if (kt + 1 < nT) {
      STAGE(kt + 1, buf ^ 1);
      asm volatile("s_waitcnt vmcnt(4)" ::: "memory");  // wait tile kt only; keep 4 in flight
    } else {
      asm volatile("s_waitcnt vmcnt(0)" ::: "memory");
    }
    __builtin_amdgcn_s_barrier();
    const int aOff = buf * 8192;
    const int bOff = 16384 + buf * 8192;

    bf16x8 af[8];
#pragma unroll
    for (int mi = 0; mi < 8; ++mi)
      af[mi] = *(const bf16x8*)&lds[aOff + (aRow + mi * 16) * 32 + kof];
    bf16x8 b0 = *(const bf16x8*)&lds[bOff + (bRow + 0) * 32 + kof];
    bf16x8 b1 = *(const bf16x8*)&lds[bOff + (bRow + 16) * 32 + kof];
    __builtin_amdgcn_s_setprio(1);
#pragma unroll
    for (int mi = 0; mi < 8; ++mi) {
      acc[mi][0] = __builtin_amdgcn_mfma_f32_16x16x32_bf16(af[mi], b0, acc[mi][0], 0, 0, 0);
      acc[mi][1] = __builtin_amdgcn_mfma_f32_16x16x32_bf16(af[mi], b1, acc[mi][1], 0, 0, 0);
    }
    __builtin_amdgcn_s_setprio(0);
    __builtin_amdgcn_s_barrier();

    bf16x8 b2 = *(const bf16x8*)&lds[bOff + (bRow + 32) * 32 + kof];
    bf16x8 b3 = *(const bf16x8*)&lds[bOff + (bRow + 48) * 32 + kof];
    __builtin_amdgcn_s_setprio(1);
#pragma unroll
    for (int mi = 0; mi < 8; ++mi) {
      acc[mi][2] = __builtin_amdgcn_mfma_f32_16x16x32_bf16(af[mi], b2, acc[mi][2], 0, 0, 0);
      acc[mi][3] = __builtin_amdgcn_mfma_f32_16x16x32_bf16(af[mi], b3, acc[mi][3], 0, 0, 0);
    }
    __builtin_amdgcn_s_setprio(0);
    // ensure this wave's ds_reads of buf are complete before anyone re-stages it
    asm volatile("s_waitcnt lgkmcnt(0)" ::: "memory");
    __builtin_amdgcn_s_barrier();
  }
#undef STAGE
#undef GLL

  // epilogue: C/D layout col=lane&15, row=(lane>>4)*4+reg
#pragma unroll
  for (int mi = 0; mi < 8; ++mi) {
#pragma unroll
    for (int ni = 0; ni < 4; ++ni) {
      int col = n0 + wn * 64 + ni * 16 + lo;
      int rb = m0 + wm * 128 + mi * 16 + hi * 4;
      float bcol = bias[col];
      f32x4 v = acc[mi][ni];
      if (MODE == 0) {
        unsigned short* ACTp = (unsigned short*)Cout;
        bool isz = ((col >> 10) & 1) == 0;  // groups 0,2 are z-gates
#pragma unroll
        for (int r = 0; r < 4; ++r) {
          float x = v[r] + bcol;
          float res;
          if (isz) res = sigm(-x);                       // a = 1 - z
          else res = (x >= 0.f) ? (x + 0.5f) : sigm(x);  // g(x)
          ACTp[(size_t)(rb + r) * 4096 + col] = f2bf(res);
        }
      } else {
        float* Op = (float*)Cout;
#pragma unroll
        for (int r = 0; r < 4; ++r) Op[(size_t)(rb + r) * 1024 + col] = v[r] + bcol;
      }
    }
  }
}

// ---------------- chunked linear scan ----------------
// ACT cols: [0,1024)=a_f  [1024,2048)=g_f  [2048,3072)=a_b  [3072,4096)=g_b
// recurrence: h = a*h + (1-a)*g ; chunk length 128, 32 chunks.

__global__ __launch_bounds__(256) void scan_phase1_kernel(const unsigned short* __restrict__ ACT,
                                                          float* __restrict__ CHA,
                                                          float* __restrict__ CHB) {
  int tid = threadIdx.x;
  int cb = blockIdx.x & 3;
  int chunk = (blockIdx.x >> 2) & 31;
  int b = (blockIdx.x >> 7) & 3;
  int dir = (blockIdx.x >> 9) & 1;
  int c = cb * 256 + tid;
  int t0 = chunk * 128;
  size_t colA = (size_t)dir * 2048 + c;
  float Ap = 1.f, Bv = 0.f;
  for (int i = 0; i < 128; ++i) {
    int t = t0 + i;
    int s = dir ? (SEQ - 1 - t) : t;
    size_t base = ((size_t)b * SEQ + s) * 4096;
    float a = bf2f(ACT[base + colA]);
    float g = bf2f(ACT[base + colA + 1024]);
    Bv = a * Bv + (1.f - a) * g;
    Ap *= a;
  }
  size_t o = ((size_t)(dir * 4 + b) * 32 + chunk) * 1024 + c;
  CHA[o] = Ap;
  CHB[o] = Bv;
}

__global__ __launch_bounds__(256) void scan_phase2_kernel(const float* __restrict__ CHA,
                                                          const float* __restrict__ CHB,
                                                          float* __restrict__ HINIT) {
  int idx = blockIdx.x * 256 + threadIdx.x;  // 8192 = dir*4096 + b*1024 + c
  int c = idx & 1023;
  int db = idx >> 10;  // dir*4 + b
  float h = 0.f;
  for (int ck = 0; ck < 32; ++ck) {
    size_t o = ((size_t)db * 32 + ck) * 1024 + c;
    HINIT[o] = h;
    h = CHA[o] * h + CHB[o];
  }
}

__global__ __launch_bounds__(256) void scan_phase3_kernel(const unsigned short* __restrict__ ACT,
                                                          const float* __restrict__ HINIT,
                                                          unsigned short* __restrict__ HCAT) {
  int tid = threadIdx.x;
  int cb = blockIdx.x & 3;
  int chunk = (blockIdx.x >> 2) & 31;
  int b = (blockIdx.x >> 7) & 3;
  int dir = (blockIdx.x >> 9) & 1;
  int c = cb * 256 + tid;
  int t0 = chunk * 128;
  size_t colA = (size_t)dir * 2048 + c;
  float h = HINIT[((size_t)(dir * 4 + b) * 32 + chunk) * 1024 + c];
  for (int i = 0; i < 128; ++i) {
    int t = t0 + i;
    int s = dir ? (SEQ - 1 - t) : t;
    size_t base = ((size_t)b * SEQ + s) * 4096;
    float a = bf2f(ACT[base + colA]);
    float g = bf2f(ACT[base + colA + 1024]);
    h = a * h + (1.f - a) * g;
    HCAT[((size_t)b * SEQ + t) * 2048 + dir * 1024 + c] = f2bf(h);
  }
}

// ---------------- launcher ----------------

extern "C" void kernel_launch(void* const* d_in, const int* in_sizes, int n_in,
                              void* d_out, int out_size, void* d_ws, size_t ws_size,
                              hipStream_t stream) {
  (void)in_sizes; (void)n_in; (void)out_size; (void)ws_size;
  const float* x     = (const float*)d_in[0];
  const float* Wz_f  = (const float*)d_in[1];
  const float* bz_f  = (const float*)d_in[2];
  const float* Wh_f  = (const float*)d_in[3];
  const float* bh_f  = (const float*)d_in[4];
  const float* Wz_b  = (const float*)d_in[5];
  const float* bz_b  = (const float*)d_in[6];
  const float* Wh_b  = (const float*)d_in[7];
  const float* bh_b  = (const float*)d_in[8];
  const float* W_out = (const float*)d_in[9];
  const float* b_out = (const float*)d_in[10];

  char* ws = (char*)d_ws;
  size_t off = 0;
  auto alloc = [&](size_t bytes) {
    char* p = ws + off;
    off = (off + bytes + 255) & ~(size_t)255;
    return p;
  };
  const size_t M = 16384;  // B*S
  unsigned short* xb    = (unsigned short*)alloc(M * 1024 * 2);        // x bf16 [M][1024]
  unsigned short* WT4   = (unsigned short*)alloc(4096ull * 1024 * 2);  // [4096][1024] K-major
  unsigned short* WTout = (unsigned short*)alloc(1024ull * 2048 * 2);  // [1024][2048] K-major
  unsigned short* ACT   = (unsigned short*)alloc(M * 4096 * 2);        // bf16 gates
  unsigned short* HCAT  = (unsigned short*)alloc(M * 2048 * 2);        // bf16 hidden concat
  float* CHA   = (float*)alloc(262144ull * 4);
  float* CHB   = (float*)alloc(262144ull * 4);
  float* HINIT = (float*)alloc(262144ull * 4);
  float* b4    = (float*)alloc(4096 * 4);

  // 1) convert x to bf16
  cvt_x_kernel<<<2048, 256, 0, stream>>>(x, xb, (int)(M * 1024 / 8));

  // 2) transpose+convert weights: WT4 groups {Wz_f, Wh_f, Wz_b, Wh_b}
  tconv32_kernel<<<dim3(32, 32), 256, 0, stream>>>(Wz_f, WT4 + 0 * 1048576, 1024, 1024);
  tconv32_kernel<<<dim3(32, 32), 256, 0, stream>>>(Wh_f, WT4 + 1 * 1048576, 1024, 1024);
  tconv32_kernel<<<dim3(32, 32), 256, 0, stream>>>(Wz_b, WT4 + 2 * 1048576, 1024, 1024);
  tconv32_kernel<<<dim3(32, 32), 256, 0, stream>>>(Wh_b, WT4 + 3 * 1048576, 1024, 1024);
  tconv32_kernel<<<dim3(32, 64), 256, 0, stream>>>(W_out, WTout, 2048, 1024);
  concat_bias_kernel<<<16, 256, 0, stream>>>(bz_f, bh_f, bz_b, bh_b, b4);

  // 3) fused input GEMM + activations -> ACT  (M=16384, N=4096, K=1024)
  gemm256_kernel<0><<<1024, 512, 0, stream>>>(xb, WT4, b4, (void*)ACT, 1024, 16);

  // 4) 3-phase linear scan -> HCAT
  scan_phase1_kernel<<<1024, 256, 0, stream>>>(ACT, CHA, CHB);
  scan_phase2_kernel<<<32, 256, 0, stream>>>(CHA, CHB, HINIT);
  scan_phase3_kernel<<<1024, 256, 0, stream>>>(ACT, HINIT, HCAT);

  // 5) output GEMM + bias -> d_out  (M=16384, N=1024, K=2048)
  gemm256_kernel<1><<<256, 512, 0, stream>>>(HCAT, WTout, b_out, d_out, 2048, 4);
}